// Round 3
// baseline (119.193 us; speedup 1.0000x reference)
//
#include <hip/hip_runtime.h>
#include <hip/hip_bf16.h>

#define NS 0.2f

// Problem sizes (fixed): B=8, S=1024, D=512, H=8, OD=64

typedef _Float16 half8 __attribute__((ext_vector_type(8)));
typedef float f32x4 __attribute__((ext_vector_type(4)));

// ---------------------------------------------------------------------------
// Fused Q/K projection: aX[row*8+h] = sum_d X[row][d]*W[h][d]
// blocks 0..2047 -> Q, 2048..4095 -> K. 4 waves/block, one row per wave.
// ---------------------------------------------------------------------------
__global__ __launch_bounds__(256) void projQK_kernel(
    const float* __restrict__ Q, const float* __restrict__ K,
    const float* __restrict__ WQ, const float* __restrict__ WK,
    float* __restrict__ aQ, float* __restrict__ aK) {
  int bid = blockIdx.x;
  const float* X;
  const float* W;
  float* aX;
  int rb;
  if (bid < 2048) { X = Q; W = WQ; aX = aQ; rb = bid; }
  else            { X = K; W = WK; aX = aK; rb = bid - 2048; }
  __shared__ __align__(16) float Wl[8 * 512];
  int t = threadIdx.x;
#pragma unroll
  for (int i = 0; i < 16; i++) Wl[i * 256 + t] = W[i * 256 + t];
  __syncthreads();
  int w = t >> 6, lane = t & 63;
  int row = rb * 4 + w;
  const float* x = X + (size_t)row * 512;
  float4 x0 = *(const float4*)(x + lane * 4);
  float4 x1 = *(const float4*)(x + 256 + lane * 4);
  float acc[8];
#pragma unroll
  for (int h = 0; h < 8; h++) {
    const float* wl = Wl + h * 512;
    float4 w0 = *(const float4*)(wl + lane * 4);
    float4 w1 = *(const float4*)(wl + 256 + lane * 4);
    float a = x0.x * w0.x + x0.y * w0.y + x0.z * w0.z + x0.w * w0.w +
              x1.x * w1.x + x1.y * w1.y + x1.z * w1.z + x1.w * w1.w;
#pragma unroll
    for (int off = 32; off > 0; off >>= 1) a += __shfl_xor(a, off);
    acc[h] = a;
  }
  if (lane == 0) {
    float* o = aX + (size_t)row * 8;
    o[0] = acc[0]; o[1] = acc[1]; o[2] = acc[2]; o[3] = acc[3];
    o[4] = acc[4]; o[5] = acc[5]; o[6] = acc[6]; o[7] = acc[7];
  }
}

// ---------------------------------------------------------------------------
// Vproj = V(8192x512) @ WV.T(512x512) -> f16 C(8192x512)
// f16 MFMA, tile 128x128, BK=32, 4 waves (2x2), each wave 64x64 = 4x4 frags.
// XOR-swizzled LDS: elem (r,k) at r*32 + ((k>>3) ^ ((r>>1)&3))*8 + (k&7)
// -> 2-way max bank aliasing on ds_read_b128 (free, m136).
// ---------------------------------------------------------------------------
__global__ __launch_bounds__(256) void vproj_mfma(
    const float* __restrict__ A, const float* __restrict__ Wv,
    _Float16* __restrict__ C) {
  __shared__ __align__(16) _Float16 As[128 * 32];
  __shared__ __align__(16) _Float16 Bs[128 * 32];
  int t = threadIdx.x;
  int m0 = blockIdx.x * 128, n0 = blockIdx.y * 128;
  int lane = t & 63, wid = t >> 6;
  int wr = wid >> 1, wc = wid & 1;
  // staging: thread t handles row sr, 16 consecutive k at half*16
  int sr = t >> 1, half = t & 1;
  const float* ap = A + (size_t)(m0 + sr) * 512 + half * 16;
  const float* bp = Wv + (size_t)(n0 + sr) * 512 + half * 16;
  int sw = (sr >> 1) & 3;
  _Float16* aw0 = As + sr * 32 + (((half * 2 + 0) ^ sw) * 8);
  _Float16* aw1 = As + sr * 32 + (((half * 2 + 1) ^ sw) * 8);
  _Float16* bw0 = Bs + sr * 32 + (((half * 2 + 0) ^ sw) * 8);
  _Float16* bw1 = Bs + sr * 32 + (((half * 2 + 1) ^ sw) * 8);
  int fr = lane & 15, fs = lane >> 4;
  f32x4 acc[4][4];
#pragma unroll
  for (int i = 0; i < 4; i++)
#pragma unroll
    for (int j = 0; j < 4; j++)
#pragma unroll
      for (int r = 0; r < 4; r++) acc[i][j][r] = 0.f;

  for (int k0 = 0; k0 < 512; k0 += 32) {
    float4 av0 = *(const float4*)(ap + k0);
    float4 av1 = *(const float4*)(ap + k0 + 4);
    float4 av2 = *(const float4*)(ap + k0 + 8);
    float4 av3 = *(const float4*)(ap + k0 + 12);
    float4 bv0 = *(const float4*)(bp + k0);
    float4 bv1 = *(const float4*)(bp + k0 + 4);
    float4 bv2 = *(const float4*)(bp + k0 + 8);
    float4 bv3 = *(const float4*)(bp + k0 + 12);
    __syncthreads();  // previous iteration's fragment reads done
    half8 h0, h1;
    h0[0] = (_Float16)av0.x; h0[1] = (_Float16)av0.y;
    h0[2] = (_Float16)av0.z; h0[3] = (_Float16)av0.w;
    h0[4] = (_Float16)av1.x; h0[5] = (_Float16)av1.y;
    h0[6] = (_Float16)av1.z; h0[7] = (_Float16)av1.w;
    h1[0] = (_Float16)av2.x; h1[1] = (_Float16)av2.y;
    h1[2] = (_Float16)av2.z; h1[3] = (_Float16)av2.w;
    h1[4] = (_Float16)av3.x; h1[5] = (_Float16)av3.y;
    h1[6] = (_Float16)av3.z; h1[7] = (_Float16)av3.w;
    *(half8*)aw0 = h0;
    *(half8*)aw1 = h1;
    h0[0] = (_Float16)bv0.x; h0[1] = (_Float16)bv0.y;
    h0[2] = (_Float16)bv0.z; h0[3] = (_Float16)bv0.w;
    h0[4] = (_Float16)bv1.x; h0[5] = (_Float16)bv1.y;
    h0[6] = (_Float16)bv1.z; h0[7] = (_Float16)bv1.w;
    h1[0] = (_Float16)bv2.x; h1[1] = (_Float16)bv2.y;
    h1[2] = (_Float16)bv2.z; h1[3] = (_Float16)bv2.w;
    h1[4] = (_Float16)bv3.x; h1[5] = (_Float16)bv3.y;
    h1[6] = (_Float16)bv3.z; h1[7] = (_Float16)bv3.w;
    *(half8*)bw0 = h0;
    *(half8*)bw1 = h1;
    __syncthreads();
    half8 af[4], bf[4];
#pragma unroll
    for (int i = 0; i < 4; i++) {
      int R = wr * 64 + i * 16 + fr;
      af[i] = *(half8*)(As + R * 32 + ((fs ^ ((R >> 1) & 3)) * 8));
    }
#pragma unroll
    for (int j = 0; j < 4; j++) {
      int Cc = wc * 64 + j * 16 + fr;
      bf[j] = *(half8*)(Bs + Cc * 32 + ((fs ^ ((Cc >> 1) & 3)) * 8));
    }
#pragma unroll
    for (int i = 0; i < 4; i++)
#pragma unroll
      for (int j = 0; j < 4; j++)
        acc[i][j] = __builtin_amdgcn_mfma_f32_16x16x32_f16(af[i], bf[j],
                                                           acc[i][j], 0, 0, 0);
  }
  // C/D layout (m89-verified): col = lane&15, row = (lane>>4)*4 + reg
#pragma unroll
  for (int i = 0; i < 4; i++)
#pragma unroll
    for (int j = 0; j < 4; j++) {
      int row = m0 + wr * 64 + i * 16 + fs * 4;
      int col = n0 + wc * 64 + j * 16 + fr;
#pragma unroll
      for (int r = 0; r < 4; r++)
        C[(size_t)(row + r) * 512 + col] = (_Float16)acc[i][j][r];
    }
}

// ---------------------------------------------------------------------------
// Per (b,h): bitonic sort of aK column (1024, ascending) with index.
// Register-resident: strides<64 via shfl_xor (no barrier), >=64 via LDS.
// ---------------------------------------------------------------------------
__global__ __launch_bounds__(1024) void sort_kernel(
    const float* __restrict__ aK, float* __restrict__ sortedA,
    int* __restrict__ sortedIdx) {
  int bh = blockIdx.x, b = bh >> 3, h = bh & 7;
  __shared__ float key[1024];
  __shared__ int idx[1024];
  int t = threadIdx.x;
  float k = aK[(size_t)(b * 1024 + t) * 8 + h];
  int id = t;
  for (int len = 2; len <= 1024; len <<= 1) {
    bool up = ((t & len) == 0);
    for (int stride = len >> 1; stride >= 64; stride >>= 1) {
      key[t] = k; idx[t] = id;
      __syncthreads();
      int p = t ^ stride;
      float k2 = key[p];
      int i2 = idx[p];
      __syncthreads();
      bool takeMin = (((t & stride) == 0) == up);
      bool take2 = takeMin ? (k2 < k) : (k2 > k);
      if (take2) { k = k2; id = i2; }
    }
    int s0 = (len >> 1) < 32 ? (len >> 1) : 32;
    for (int stride = s0; stride >= 1; stride >>= 1) {
      float k2 = __shfl_xor(k, stride);
      int i2 = __shfl_xor(id, stride);
      bool takeMin = (((t & stride) == 0) == up);
      bool take2 = takeMin ? (k2 < k) : (k2 > k);
      if (take2) { k = k2; id = i2; }
    }
  }
  sortedA[bh * 1024 + t] = k;
  sortedIdx[bh * 1024 + t] = id;
}

// ---------------------------------------------------------------------------
// Per (bh, d-slice of 16): two-level prefix/suffix sums over sorted keys,
// max-subtracted exponentials, f16 U output.
//   U1[i] = sum_{j>=i} e^{a_j-amax} Vp[idx_j]   (suffix)
//   U2[i] = sum_{j<i}  e^{NS(a_j-amax)} Vp[idx_j] (prefix)
// grid 256 = bh*4+dg; block 256 = 16 chunks x 16 d; 64 keys/chunk.
// ---------------------------------------------------------------------------
__global__ __launch_bounds__(256) void prefix_kernel(
    const float* __restrict__ sortedA, const int* __restrict__ sortedIdx,
    const _Float16* __restrict__ Vp, _Float16* __restrict__ U1,
    _Float16* __restrict__ U2, float* __restrict__ S1,
    float* __restrict__ S2) {
  int blk = blockIdx.x;
  int bh = blk >> 2, dg = blk & 3;
  int b = bh >> 3, h = bh & 7;
  __shared__ float E1[1024], E2[1024];
  __shared__ int IDX[1024];
  __shared__ float tot1[16][16], tot2[16][16];
  __shared__ float off1R[16][16], off2[16][16];
  __shared__ float stot1[16], stot2[16], soff1R[16], soff2[16];
  int t = threadIdx.x;
  float amax = sortedA[bh * 1024 + 1023];
  for (int i = t; i < 1024; i += 256) {
    float a = sortedA[bh * 1024 + i] - amax;
    E1[i] = __expf(a);
    E2[i] = __expf(NS * a);
    IDX[i] = sortedIdx[bh * 1024 + i];
  }
  __syncthreads();
  int c = t >> 4, d = t & 15;
  int dd = dg * 16 + d;
  const _Float16* vbase = Vp + (size_t)b * 1024 * 512 + h * 64 + dd;
  // phase 1: chunk totals
  float t1 = 0.f, t2 = 0.f, s1 = 0.f, s2 = 0.f;
#pragma unroll 4
  for (int j = 0; j < 64; j++) {
    int i = c * 64 + j;
    float v = (float)vbase[(size_t)IDX[i] * 512];
    float e1 = E1[i], e2 = E2[i];
    t1 += e1 * v; t2 += e2 * v;
    s1 += e1; s2 += e2;
  }
  tot1[c][d] = t1; tot2[c][d] = t2;
  if (d == 0) { stot1[c] = s1; stot2[c] = s2; }
  __syncthreads();
  // phase 2: scan over 16 chunks
  if (t < 16) {
    float sfx = 0.f, pfx = 0.f;
    for (int cc = 15; cc >= 0; cc--) { off1R[cc][t] = sfx; sfx += tot1[cc][t]; }
    for (int cc = 0; cc < 16; cc++) { off2[cc][t] = pfx; pfx += tot2[cc][t]; }
  } else if (t == 16) {
    float sfx = 0.f;
    for (int cc = 15; cc >= 0; cc--) { soff1R[cc] = sfx; sfx += stot1[cc]; }
  } else if (t == 17) {
    float pfx = 0.f;
    for (int cc = 0; cc < 16; cc++) { soff2[cc] = pfx; pfx += stot2[cc]; }
  }
  __syncthreads();
  // phase 3: emit
  float acc1 = 0.f, acc2 = off2[c][d];
  float o1r = off1R[c][d], tt1 = tot1[c][d];
  float sacc1 = 0.f, sacc2 = soff2[c];
  float so1r = soff1R[c], st1 = stot1[c];
  _Float16* u1base = U1 + (size_t)bh * 1025 * 64 + dd;
  _Float16* u2base = U2 + (size_t)bh * 1025 * 64 + dd;
  bool dosc = (d == 0) && (dg == 0);
#pragma unroll 4
  for (int j = 0; j < 64; j++) {
    int i = c * 64 + j;
    float v = (float)vbase[(size_t)IDX[i] * 512];
    float e1 = E1[i], e2 = E2[i];
    u1base[(size_t)i * 64] = (_Float16)(o1r + (tt1 - acc1));
    acc1 += e1 * v;
    acc2 += e2 * v;
    u2base[(size_t)(i + 1) * 64] = (_Float16)acc2;
    if (dosc) S1[bh * 1025 + i] = so1r + (st1 - sacc1);
    sacc1 += e1;
    sacc2 += e2;
    if (dosc) S2[bh * 1025 + i + 1] = sacc2;
  }
  if (c == 0) {
    u1base[(size_t)1024 * 64] = (_Float16)0.f;
    u2base[0] = (_Float16)0.f;
  }
  if (t == 0 && dg == 0) {
    S1[bh * 1025 + 1024] = 0.f;
    S2[bh * 1025] = 0.f;
  }
}

// ---------------------------------------------------------------------------
// out = (e^{x+amax} U1[ix] + e^{NS(x+amax)} U2[ix]) / (same with S) + bias
// one wave per (b,q,h); fused binary search for ix (L2-resident sortedA).
// ---------------------------------------------------------------------------
__global__ __launch_bounds__(256) void final_kernel(
    const float* __restrict__ aQ, const float* __restrict__ sortedA,
    const _Float16* __restrict__ U1, const _Float16* __restrict__ U2,
    const float* __restrict__ S1, const float* __restrict__ S2,
    const float* __restrict__ bias, float* __restrict__ out) {
  int t = threadIdx.x;
  int w = t >> 6, d = t & 63;
  int task = blockIdx.x * 4 + w;  // b*8192 + q*8 + h
  int h = task & 7, b = task >> 13;
  int q = (task >> 3) & 1023;
  int bh = b * 8 + h;
  const float* sa = sortedA + bh * 1024;
  float x = aQ[task];
  float negx = -x;
  int lo = 0, hi = 1024;
  while (lo < hi) {
    int mid = (lo + hi) >> 1;
    if (sa[mid] <= negx) lo = mid + 1; else hi = mid;
  }
  int ix = lo;
  float amax = sa[1023];
  float xs = x + amax;
  float ex = __expf(xs), e2x = __expf(NS * xs);
  float u1 = (float)U1[((size_t)bh * 1025 + ix) * 64 + d];
  float u2 = (float)U2[((size_t)bh * 1025 + ix) * 64 + d];
  float Z = ex * S1[bh * 1025 + ix] + e2x * S2[bh * 1025 + ix];
  float val = (ex * u1 + e2x * u2) / Z + bias[h * 64 + d];
  out[((size_t)(b * 1024 + q)) * 512 + h * 64 + d] = val;
}

// ---------------------------------------------------------------------------
// Fallback path kernels (small ws): f32 GEMM + direct attention
// ---------------------------------------------------------------------------
__global__ __launch_bounds__(256) void vproj_gemm(
    const float* __restrict__ A, const float* __restrict__ Wv,
    float* __restrict__ C) {
  __shared__ __align__(16) float As[16][68];
  __shared__ __align__(16) float Bs[16][68];
  int t = threadIdx.x;
  int m0 = blockIdx.x * 64, n0 = blockIdx.y * 64;
  int tx = t & 15, ty = t >> 4;
  int lr = t >> 2, lk = (t & 3) * 4;
  float acc[4][4] = {{0.f}};
  const float* ap = A + (size_t)(m0 + lr) * 512 + lk;
  const float* bp = Wv + (size_t)(n0 + lr) * 512 + lk;
  for (int k0 = 0; k0 < 512; k0 += 16) {
    float4 av = *(const float4*)(ap + k0);
    float4 bv = *(const float4*)(bp + k0);
    __syncthreads();
    As[lk + 0][lr] = av.x; As[lk + 1][lr] = av.y;
    As[lk + 2][lr] = av.z; As[lk + 3][lr] = av.w;
    Bs[lk + 0][lr] = bv.x; Bs[lk + 1][lr] = bv.y;
    Bs[lk + 2][lr] = bv.z; Bs[lk + 3][lr] = bv.w;
    __syncthreads();
#pragma unroll
    for (int kk = 0; kk < 16; kk++) {
      float4 a4 = *(const float4*)&As[kk][ty * 4];
      float4 b4 = *(const float4*)&Bs[kk][tx * 4];
      float aa[4] = {a4.x, a4.y, a4.z, a4.w};
      float bb[4] = {b4.x, b4.y, b4.z, b4.w};
#pragma unroll
      for (int i = 0; i < 4; i++)
#pragma unroll
        for (int j = 0; j < 4; j++) acc[i][j] += aa[i] * bb[j];
    }
  }
#pragma unroll
  for (int i = 0; i < 4; i++) {
    float4 o = {acc[i][0], acc[i][1], acc[i][2], acc[i][3]};
    *(float4*)(C + (size_t)(m0 + ty * 4 + i) * 512 + n0 + tx * 4) = o;
  }
}

__global__ __launch_bounds__(256) void direct_kernel(
    const float* __restrict__ aQ, const float* __restrict__ aK,
    const float* __restrict__ Vp, const float* __restrict__ bias,
    float* __restrict__ out) {
  int id = blockIdx.x;
  int qt = id & 15, h = (id >> 4) & 7, b = id >> 7;
  __shared__ float AK[1024], E1s[1024], E2s[1024];
  __shared__ __align__(16) float VT[128][64];
  __shared__ float XQ[64];
  int t = threadIdx.x;
  for (int i = t; i < 1024; i += 256) {
    float a = aK[(size_t)(b * 1024 + i) * 8 + h];
    AK[i] = a; E1s[i] = __expf(a); E2s[i] = __expf(NS * a);
  }
  if (t < 64) XQ[t] = aQ[(size_t)(b * 1024 + qt * 64 + t) * 8 + h];
  __syncthreads();
  int w = t >> 6, d = t & 63;
  float xq[16], ex[16], e2x[16], acc[16], z[16];
#pragma unroll
  for (int qi = 0; qi < 16; qi++) {
    float x = XQ[w * 16 + qi];
    xq[qi] = x; ex[qi] = __expf(x); e2x[qi] = __expf(NS * x);
    acc[qi] = 0.f; z[qi] = 0.f;
  }
  for (int kt = 0; kt < 8; kt++) {
    __syncthreads();
    for (int i = t; i < 128 * 64; i += 256) {
      VT[i >> 6][i & 63] =
          Vp[(size_t)(b * 1024 + kt * 128 + (i >> 6)) * 512 + h * 64 + (i & 63)];
    }
    __syncthreads();
    for (int kk = 0; kk < 128; kk++) {
      int k = kt * 128 + kk;
      float a = AK[k], e1 = E1s[k], e2 = E2s[k];
      float v = VT[kk][d];
#pragma unroll
      for (int qi = 0; qi < 16; qi++) {
        float wsel = (a + xq[qi] > 0.f) ? (ex[qi] * e1) : (e2x[qi] * e2);
        acc[qi] += wsel * v;
        z[qi] += wsel;
      }
    }
  }
#pragma unroll
  for (int qi = 0; qi < 16; qi++) {
    int q = qt * 64 + w * 16 + qi;
    out[(size_t)(b * 1024 + q) * 512 + h * 64 + d] =
        acc[qi] / z[qi] + bias[h * 64 + d];
  }
}

// ---------------------------------------------------------------------------
extern "C" void kernel_launch(void* const* d_in, const int* in_sizes, int n_in,
                              void* d_out, int out_size, void* d_ws,
                              size_t ws_size, hipStream_t stream) {
  const float* Q = (const float*)d_in[0];
  const float* K = (const float*)d_in[1];
  const float* V = (const float*)d_in[2];
  const float* WQ = (const float*)d_in[3];
  const float* WK = (const float*)d_in[4];
  const float* WV = (const float*)d_in[5];
  const float* bias = (const float*)d_in[6];
  float* out = (float*)d_out;
  char* ws = (char*)d_ws;

  // byte offsets (16B aligned)
  const size_t oAQ = 0;                       // f32 [8192][8]   256 KB
  const size_t oAK = 262144;                  // f32 [8192][8]   256 KB
  const size_t oSA = 524288;                  // f32 [64][1024]  256 KB
  const size_t oSI = 786432;                  // i32 [64][1024]  256 KB
  const size_t oS1 = 1048576;                 // f32 [64][1025]  ~257 KB (pad 288K)
  const size_t oS2 = oS1 + 294912;
  const size_t oVP = oS2 + 294912;            // f16 [8192][512] 8 MB
  const size_t oU1 = oVP + 8388608;           // f16 [64][1025][64] ~8 MB
  const size_t oU2 = oU1 + 8396800;
  const size_t NEED_MAIN = oU2 + 8396800;     // ~27 MB
  const size_t NEED_FB = 524288 + 16777216;   // ~17 MB

  if (ws_size >= NEED_MAIN) {
    float* aQ = (float*)(ws + oAQ);
    float* aK = (float*)(ws + oAK);
    float* sA = (float*)(ws + oSA);
    int* sI = (int*)(ws + oSI);
    float* S1 = (float*)(ws + oS1);
    float* S2 = (float*)(ws + oS2);
    _Float16* Vp = (_Float16*)(ws + oVP);
    _Float16* U1 = (_Float16*)(ws + oU1);
    _Float16* U2 = (_Float16*)(ws + oU2);
    hipLaunchKernelGGL(projQK_kernel, dim3(4096), dim3(256), 0, stream, Q, K,
                       WQ, WK, aQ, aK);
    hipLaunchKernelGGL(sort_kernel, dim3(64), dim3(1024), 0, stream, aK, sA, sI);
    hipLaunchKernelGGL(vproj_mfma, dim3(64, 4), dim3(256), 0, stream, V, WV, Vp);
    hipLaunchKernelGGL(prefix_kernel, dim3(256), dim3(256), 0, stream, sA, sI,
                       Vp, U1, U2, S1, S2);
    hipLaunchKernelGGL(final_kernel, dim3(16384), dim3(256), 0, stream, aQ, sA,
                       U1, U2, S1, S2, bias, out);
  } else if (ws_size >= NEED_FB) {
    float* aQ = (float*)(ws + 0);
    float* aK = (float*)(ws + 262144);
    float* Vpf = (float*)(ws + 524288);
    hipLaunchKernelGGL(projQK_kernel, dim3(4096), dim3(256), 0, stream, Q, K,
                       WQ, WK, aQ, aK);
    hipLaunchKernelGGL(vproj_gemm, dim3(128, 8), dim3(256), 0, stream, V, WV,
                       Vpf);
    hipLaunchKernelGGL(direct_kernel, dim3(1024), dim3(256), 0, stream, aQ, aK,
                       Vpf, bias, out);
  }
}

// Round 4
// 110.365 us; speedup vs baseline: 1.0800x; 1.0800x over previous
//
#include <hip/hip_runtime.h>
#include <hip/hip_bf16.h>

#define NS 0.2f

// Problem sizes (fixed): B=8, S=1024, D=512, H=8, OD=64

typedef _Float16 half8 __attribute__((ext_vector_type(8)));
typedef float f32x4 __attribute__((ext_vector_type(4)));

// ---------------------------------------------------------------------------
// Fused Q/K projection: aX[row*8+h] = sum_d X[row][d]*W[h][d]
// blocks 0..2047 -> Q, 2048..4095 -> K. 4 waves/block, one row per wave.
// ---------------------------------------------------------------------------
__global__ __launch_bounds__(256) void projQK_kernel(
    const float* __restrict__ Q, const float* __restrict__ K,
    const float* __restrict__ WQ, const float* __restrict__ WK,
    float* __restrict__ aQ, float* __restrict__ aK) {
  int bid = blockIdx.x;
  const float* X;
  const float* W;
  float* aX;
  int rb;
  if (bid < 2048) { X = Q; W = WQ; aX = aQ; rb = bid; }
  else            { X = K; W = WK; aX = aK; rb = bid - 2048; }
  __shared__ __align__(16) float Wl[8 * 512];
  int t = threadIdx.x;
#pragma unroll
  for (int i = 0; i < 16; i++) Wl[i * 256 + t] = W[i * 256 + t];
  __syncthreads();
  int w = t >> 6, lane = t & 63;
  int row = rb * 4 + w;
  const float* x = X + (size_t)row * 512;
  float4 x0 = *(const float4*)(x + lane * 4);
  float4 x1 = *(const float4*)(x + 256 + lane * 4);
  float acc[8];
#pragma unroll
  for (int h = 0; h < 8; h++) {
    const float* wl = Wl + h * 512;
    float4 w0 = *(const float4*)(wl + lane * 4);
    float4 w1 = *(const float4*)(wl + 256 + lane * 4);
    float a = x0.x * w0.x + x0.y * w0.y + x0.z * w0.z + x0.w * w0.w +
              x1.x * w1.x + x1.y * w1.y + x1.z * w1.z + x1.w * w1.w;
#pragma unroll
    for (int off = 32; off > 0; off >>= 1) a += __shfl_xor(a, off);
    acc[h] = a;
  }
  if (lane == 0) {
    float* o = aX + (size_t)row * 8;
    o[0] = acc[0]; o[1] = acc[1]; o[2] = acc[2]; o[3] = acc[3];
    o[4] = acc[4]; o[5] = acc[5]; o[6] = acc[6]; o[7] = acc[7];
  }
}

// ---------------------------------------------------------------------------
// Vproj = V(8192x512) @ WV.T(512x512) -> f16 C(8192x512)
// f16 MFMA, tile 128x128, BK=32, 4 waves (2x2), each wave 64x64 = 4x4 frags.
// XOR-swizzled LDS: elem (r,k) at r*32 + ((k>>3) ^ ((r>>1)&3))*8 + (k&7)
// ---------------------------------------------------------------------------
__global__ __launch_bounds__(256) void vproj_mfma(
    const float* __restrict__ A, const float* __restrict__ Wv,
    _Float16* __restrict__ C) {
  __shared__ __align__(16) _Float16 As[128 * 32];
  __shared__ __align__(16) _Float16 Bs[128 * 32];
  int t = threadIdx.x;
  int m0 = blockIdx.x * 128, n0 = blockIdx.y * 128;
  int lane = t & 63, wid = t >> 6;
  int wr = wid >> 1, wc = wid & 1;
  int sr = t >> 1, half = t & 1;
  const float* ap = A + (size_t)(m0 + sr) * 512 + half * 16;
  const float* bp = Wv + (size_t)(n0 + sr) * 512 + half * 16;
  int sw = (sr >> 1) & 3;
  _Float16* aw0 = As + sr * 32 + (((half * 2 + 0) ^ sw) * 8);
  _Float16* aw1 = As + sr * 32 + (((half * 2 + 1) ^ sw) * 8);
  _Float16* bw0 = Bs + sr * 32 + (((half * 2 + 0) ^ sw) * 8);
  _Float16* bw1 = Bs + sr * 32 + (((half * 2 + 1) ^ sw) * 8);
  int fr = lane & 15, fs = lane >> 4;
  f32x4 acc[4][4];
#pragma unroll
  for (int i = 0; i < 4; i++)
#pragma unroll
    for (int j = 0; j < 4; j++)
#pragma unroll
      for (int r = 0; r < 4; r++) acc[i][j][r] = 0.f;

  for (int k0 = 0; k0 < 512; k0 += 32) {
    float4 av0 = *(const float4*)(ap + k0);
    float4 av1 = *(const float4*)(ap + k0 + 4);
    float4 av2 = *(const float4*)(ap + k0 + 8);
    float4 av3 = *(const float4*)(ap + k0 + 12);
    float4 bv0 = *(const float4*)(bp + k0);
    float4 bv1 = *(const float4*)(bp + k0 + 4);
    float4 bv2 = *(const float4*)(bp + k0 + 8);
    float4 bv3 = *(const float4*)(bp + k0 + 12);
    __syncthreads();
    half8 h0, h1;
    h0[0] = (_Float16)av0.x; h0[1] = (_Float16)av0.y;
    h0[2] = (_Float16)av0.z; h0[3] = (_Float16)av0.w;
    h0[4] = (_Float16)av1.x; h0[5] = (_Float16)av1.y;
    h0[6] = (_Float16)av1.z; h0[7] = (_Float16)av1.w;
    h1[0] = (_Float16)av2.x; h1[1] = (_Float16)av2.y;
    h1[2] = (_Float16)av2.z; h1[3] = (_Float16)av2.w;
    h1[4] = (_Float16)av3.x; h1[5] = (_Float16)av3.y;
    h1[6] = (_Float16)av3.z; h1[7] = (_Float16)av3.w;
    *(half8*)aw0 = h0;
    *(half8*)aw1 = h1;
    h0[0] = (_Float16)bv0.x; h0[1] = (_Float16)bv0.y;
    h0[2] = (_Float16)bv0.z; h0[3] = (_Float16)bv0.w;
    h0[4] = (_Float16)bv1.x; h0[5] = (_Float16)bv1.y;
    h0[6] = (_Float16)bv1.z; h0[7] = (_Float16)bv1.w;
    h1[0] = (_Float16)bv2.x; h1[1] = (_Float16)bv2.y;
    h1[2] = (_Float16)bv2.z; h1[3] = (_Float16)bv2.w;
    h1[4] = (_Float16)bv3.x; h1[5] = (_Float16)bv3.y;
    h1[6] = (_Float16)bv3.z; h1[7] = (_Float16)bv3.w;
    *(half8*)bw0 = h0;
    *(half8*)bw1 = h1;
    __syncthreads();
    half8 af[4], bf[4];
#pragma unroll
    for (int i = 0; i < 4; i++) {
      int R = wr * 64 + i * 16 + fr;
      af[i] = *(half8*)(As + R * 32 + ((fs ^ ((R >> 1) & 3)) * 8));
    }
#pragma unroll
    for (int j = 0; j < 4; j++) {
      int Cc = wc * 64 + j * 16 + fr;
      bf[j] = *(half8*)(Bs + Cc * 32 + ((fs ^ ((Cc >> 1) & 3)) * 8));
    }
#pragma unroll
    for (int i = 0; i < 4; i++)
#pragma unroll
      for (int j = 0; j < 4; j++)
        acc[i][j] = __builtin_amdgcn_mfma_f32_16x16x32_f16(af[i], bf[j],
                                                           acc[i][j], 0, 0, 0);
  }
  // C/D layout (m89-verified): col = lane&15, row = (lane>>4)*4 + reg
#pragma unroll
  for (int i = 0; i < 4; i++)
#pragma unroll
    for (int j = 0; j < 4; j++) {
      int row = m0 + wr * 64 + i * 16 + fs * 4;
      int col = n0 + wc * 64 + j * 16 + fr;
#pragma unroll
      for (int r = 0; r < 4; r++)
        C[(size_t)(row + r) * 512 + col] = (_Float16)acc[i][j][r];
    }
}

// ---------------------------------------------------------------------------
// Per (b,h): bitonic sort of aK column (1024, ascending) with index.
// strides<64 via shfl_xor (no barrier), >=64 via LDS.
// ---------------------------------------------------------------------------
__global__ __launch_bounds__(1024) void sort_kernel(
    const float* __restrict__ aK, float* __restrict__ sortedA,
    int* __restrict__ sortedIdx) {
  int bh = blockIdx.x, b = bh >> 3, h = bh & 7;
  __shared__ float key[1024];
  __shared__ int idx[1024];
  int t = threadIdx.x;
  float k = aK[(size_t)(b * 1024 + t) * 8 + h];
  int id = t;
  for (int len = 2; len <= 1024; len <<= 1) {
    bool up = ((t & len) == 0);
    for (int stride = len >> 1; stride >= 64; stride >>= 1) {
      key[t] = k; idx[t] = id;
      __syncthreads();
      int p = t ^ stride;
      float k2 = key[p];
      int i2 = idx[p];
      __syncthreads();
      bool takeMin = (((t & stride) == 0) == up);
      bool take2 = takeMin ? (k2 < k) : (k2 > k);
      if (take2) { k = k2; id = i2; }
    }
    int s0 = (len >> 1) < 32 ? (len >> 1) : 32;
    for (int stride = s0; stride >= 1; stride >>= 1) {
      float k2 = __shfl_xor(k, stride);
      int i2 = __shfl_xor(id, stride);
      bool takeMin = (((t & stride) == 0) == up);
      bool take2 = takeMin ? (k2 < k) : (k2 > k);
      if (take2) { k = k2; id = i2; }
    }
  }
  sortedA[bh * 1024 + t] = k;
  sortedIdx[bh * 1024 + t] = id;
}

// ---------------------------------------------------------------------------
// Hierarchical scan stage A: per-chunk totals.
// 32 chunks of 32 keys per bh. grid 512 = bh*8+g (g: 4 chunks of the 32),
// block 256 = 4 chunks x 64 d. Full 64-wide d -> 128B-line Vp gathers.
//   ctot1[bh][cc][d] = sum_{j in chunk} e1_j * Vp[idx_j][d]
//   ctot2 analog with e2; sctot scalar analogs.
// ---------------------------------------------------------------------------
__global__ __launch_bounds__(256) void prefixA_kernel(
    const float* __restrict__ sortedA, const int* __restrict__ sortedIdx,
    const _Float16* __restrict__ Vp, float* __restrict__ ctot1,
    float* __restrict__ ctot2, float* __restrict__ sctot1,
    float* __restrict__ sctot2) {
  int blk = blockIdx.x;
  int bh = blk >> 3, g = blk & 7;
  int b = bh >> 3, h = bh & 7;
  __shared__ float E1[128], E2[128];
  __shared__ int IDX[128];
  int t = threadIdx.x;
  float amax = sortedA[bh * 1024 + 1023];
  if (t < 128) {
    int gi = bh * 1024 + g * 128 + t;
    float a = sortedA[gi] - amax;
    E1[t] = __expf(a);
    E2[t] = __expf(NS * a);
    IDX[t] = sortedIdx[gi];
  }
  __syncthreads();
  int c = t >> 6, d = t & 63;
  const _Float16* vbase = Vp + (size_t)b * 1024 * 512 + h * 64 + d;
  float t1 = 0.f, t2 = 0.f, s1 = 0.f, s2 = 0.f;
#pragma unroll 8
  for (int j = 0; j < 32; j++) {
    int il = c * 32 + j;
    float v = (float)vbase[(size_t)IDX[il] * 512];
    float e1 = E1[il], e2 = E2[il];
    t1 += e1 * v; t2 += e2 * v;
    s1 += e1; s2 += e2;
  }
  int cc = g * 4 + c;
  ctot1[(bh * 32 + cc) * 64 + d] = t1;
  ctot2[(bh * 32 + cc) * 64 + d] = t2;
  if (d == 0) { sctot1[bh * 32 + cc] = s1; sctot2[bh * 32 + cc] = s2; }
}

// ---------------------------------------------------------------------------
// Hierarchical scan stage C: register scan of 32 chunk totals (wave-uniform
// branches, coalesced), re-gather, emit U1/U2 (f16, full-line writes) + S1/S2.
//   U1[i] = suffix sum from i of e1*v; U2[i] = prefix sum before i of e2*v.
// ---------------------------------------------------------------------------
__global__ __launch_bounds__(256) void prefixC_kernel(
    const float* __restrict__ sortedA, const int* __restrict__ sortedIdx,
    const _Float16* __restrict__ Vp, const float* __restrict__ ctot1,
    const float* __restrict__ ctot2, const float* __restrict__ sctot1,
    const float* __restrict__ sctot2, _Float16* __restrict__ U1,
    _Float16* __restrict__ U2, float* __restrict__ S1,
    float* __restrict__ S2) {
  int blk = blockIdx.x;
  int bh = blk >> 3, g = blk & 7;
  int b = bh >> 3, h = bh & 7;
  __shared__ float E1[128], E2[128];
  __shared__ int IDX[128];
  int t = threadIdx.x;
  float amax = sortedA[bh * 1024 + 1023];
  if (t < 128) {
    int gi = bh * 1024 + g * 128 + t;
    float a = sortedA[gi] - amax;
    E1[t] = __expf(a);
    E2[t] = __expf(NS * a);
    IDX[t] = sortedIdx[gi];
  }
  __syncthreads();
  int c = t >> 6, d = t & 63;   // c is wave-uniform
  int cc = g * 4 + c;
  // cross-chunk offsets (global scan over 32 chunks, in registers)
  float o1r = 0.f, o2 = 0.f, tt1 = 0.f;
  float so1r = 0.f, so2 = 0.f, st1 = 0.f;
#pragma unroll
  for (int k = 0; k < 32; k++) {
    float v1 = ctot1[(bh * 32 + k) * 64 + d];
    float sv1 = sctot1[bh * 32 + k];
    if (k > cc) { o1r += v1; so1r += sv1; }
    if (k == cc) { tt1 = v1; st1 = sv1; }
    if (k < cc) {
      o2 += ctot2[(bh * 32 + k) * 64 + d];
      so2 += sctot2[bh * 32 + k];
    }
  }
  const _Float16* vbase = Vp + (size_t)b * 1024 * 512 + h * 64 + d;
  float acc1 = 0.f, acc2 = o2;
  float sacc1 = 0.f, sacc2 = so2;
  _Float16* u1base = U1 + (size_t)bh * 1025 * 64 + d;
  _Float16* u2base = U2 + (size_t)bh * 1025 * 64 + d;
  bool dosc = (d == 0);
#pragma unroll 4
  for (int j = 0; j < 32; j++) {
    int il = c * 32 + j;      // local key 0..127
    int i = g * 128 + il;     // global key 0..1023
    float v = (float)vbase[(size_t)IDX[il] * 512];
    float e1 = E1[il], e2 = E2[il];
    u1base[(size_t)i * 64] = (_Float16)(o1r + (tt1 - acc1));
    acc1 += e1 * v;
    acc2 += e2 * v;
    u2base[(size_t)(i + 1) * 64] = (_Float16)acc2;
    if (dosc) S1[bh * 1025 + i] = so1r + (st1 - sacc1);
    sacc1 += e1;
    sacc2 += e2;
    if (dosc) S2[bh * 1025 + i + 1] = sacc2;
  }
  if (g == 0 && c == 0) {
    u1base[(size_t)1024 * 64] = (_Float16)0.f;
    u2base[0] = (_Float16)0.f;
    if (t == 0) {
      S1[bh * 1025 + 1024] = 0.f;
      S2[bh * 1025] = 0.f;
    }
  }
}

// ---------------------------------------------------------------------------
// out = (e^{x+amax} U1[ix] + e^{NS(x+amax)} U2[ix]) / (same with S) + bias
// one wave per (b,q,h); fused binary search for ix (L2-resident sortedA).
// ---------------------------------------------------------------------------
__global__ __launch_bounds__(256) void final_kernel(
    const float* __restrict__ aQ, const float* __restrict__ sortedA,
    const _Float16* __restrict__ U1, const _Float16* __restrict__ U2,
    const float* __restrict__ S1, const float* __restrict__ S2,
    const float* __restrict__ bias, float* __restrict__ out) {
  int t = threadIdx.x;
  int w = t >> 6, d = t & 63;
  int task = blockIdx.x * 4 + w;  // b*8192 + q*8 + h
  int h = task & 7, b = task >> 13;
  int q = (task >> 3) & 1023;
  int bh = b * 8 + h;
  const float* sa = sortedA + bh * 1024;
  float x = aQ[task];
  float negx = -x;
  int lo = 0, hi = 1024;
  while (lo < hi) {
    int mid = (lo + hi) >> 1;
    if (sa[mid] <= negx) lo = mid + 1; else hi = mid;
  }
  int ix = lo;
  float amax = sa[1023];
  float xs = x + amax;
  float ex = __expf(xs), e2x = __expf(NS * xs);
  float u1 = (float)U1[((size_t)bh * 1025 + ix) * 64 + d];
  float u2 = (float)U2[((size_t)bh * 1025 + ix) * 64 + d];
  float Z = ex * S1[bh * 1025 + ix] + e2x * S2[bh * 1025 + ix];
  float val = (ex * u1 + e2x * u2) / Z + bias[h * 64 + d];
  out[((size_t)(b * 1024 + q)) * 512 + h * 64 + d] = val;
}

// ---------------------------------------------------------------------------
// Fallback path kernels (small ws): f32 GEMM + direct attention
// ---------------------------------------------------------------------------
__global__ __launch_bounds__(256) void vproj_gemm(
    const float* __restrict__ A, const float* __restrict__ Wv,
    float* __restrict__ C) {
  __shared__ __align__(16) float As[16][68];
  __shared__ __align__(16) float Bs[16][68];
  int t = threadIdx.x;
  int m0 = blockIdx.x * 64, n0 = blockIdx.y * 64;
  int tx = t & 15, ty = t >> 4;
  int lr = t >> 2, lk = (t & 3) * 4;
  float acc[4][4] = {{0.f}};
  const float* ap = A + (size_t)(m0 + lr) * 512 + lk;
  const float* bp = Wv + (size_t)(n0 + lr) * 512 + lk;
  for (int k0 = 0; k0 < 512; k0 += 16) {
    float4 av = *(const float4*)(ap + k0);
    float4 bv = *(const float4*)(bp + k0);
    __syncthreads();
    As[lk + 0][lr] = av.x; As[lk + 1][lr] = av.y;
    As[lk + 2][lr] = av.z; As[lk + 3][lr] = av.w;
    Bs[lk + 0][lr] = bv.x; Bs[lk + 1][lr] = bv.y;
    Bs[lk + 2][lr] = bv.z; Bs[lk + 3][lr] = bv.w;
    __syncthreads();
#pragma unroll
    for (int kk = 0; kk < 16; kk++) {
      float4 a4 = *(const float4*)&As[kk][ty * 4];
      float4 b4 = *(const float4*)&Bs[kk][tx * 4];
      float aa[4] = {a4.x, a4.y, a4.z, a4.w};
      float bb[4] = {b4.x, b4.y, b4.z, b4.w};
#pragma unroll
      for (int i = 0; i < 4; i++)
#pragma unroll
        for (int j = 0; j < 4; j++) acc[i][j] += aa[i] * bb[j];
    }
  }
#pragma unroll
  for (int i = 0; i < 4; i++) {
    float4 o = {acc[i][0], acc[i][1], acc[i][2], acc[i][3]};
    *(float4*)(C + (size_t)(m0 + ty * 4 + i) * 512 + n0 + tx * 4) = o;
  }
}

__global__ __launch_bounds__(256) void direct_kernel(
    const float* __restrict__ aQ, const float* __restrict__ aK,
    const float* __restrict__ Vp, const float* __restrict__ bias,
    float* __restrict__ out) {
  int id = blockIdx.x;
  int qt = id & 15, h = (id >> 4) & 7, b = id >> 7;
  __shared__ float AK[1024], E1s[1024], E2s[1024];
  __shared__ __align__(16) float VT[128][64];
  __shared__ float XQ[64];
  int t = threadIdx.x;
  for (int i = t; i < 1024; i += 256) {
    float a = aK[(size_t)(b * 1024 + i) * 8 + h];
    AK[i] = a; E1s[i] = __expf(a); E2s[i] = __expf(NS * a);
  }
  if (t < 64) XQ[t] = aQ[(size_t)(b * 1024 + qt * 64 + t) * 8 + h];
  __syncthreads();
  int w = t >> 6, d = t & 63;
  float xq[16], ex[16], e2x[16], acc[16], z[16];
#pragma unroll
  for (int qi = 0; qi < 16; qi++) {
    float x = XQ[w * 16 + qi];
    xq[qi] = x; ex[qi] = __expf(x); e2x[qi] = __expf(NS * x);
    acc[qi] = 0.f; z[qi] = 0.f;
  }
  for (int kt = 0; kt < 8; kt++) {
    __syncthreads();
    for (int i = t; i < 128 * 64; i += 256) {
      VT[i >> 6][i & 63] =
          Vp[(size_t)(b * 1024 + kt * 128 + (i >> 6)) * 512 + h * 64 + (i & 63)];
    }
    __syncthreads();
    for (int kk = 0; kk < 128; kk++) {
      int k = kt * 128 + kk;
      float a = AK[k], e1 = E1s[k], e2 = E2s[k];
      float v = VT[kk][d];
#pragma unroll
      for (int qi = 0; qi < 16; qi++) {
        float wsel = (a + xq[qi] > 0.f) ? (ex[qi] * e1) : (e2x[qi] * e2);
        acc[qi] += wsel * v;
        z[qi] += wsel;
      }
    }
  }
#pragma unroll
  for (int qi = 0; qi < 16; qi++) {
    int q = qt * 64 + w * 16 + qi;
    out[(size_t)(b * 1024 + q) * 512 + h * 64 + d] =
        acc[qi] / z[qi] + bias[h * 64 + d];
  }
}

// ---------------------------------------------------------------------------
extern "C" void kernel_launch(void* const* d_in, const int* in_sizes, int n_in,
                              void* d_out, int out_size, void* d_ws,
                              size_t ws_size, hipStream_t stream) {
  const float* Q = (const float*)d_in[0];
  const float* K = (const float*)d_in[1];
  const float* V = (const float*)d_in[2];
  const float* WQ = (const float*)d_in[3];
  const float* WK = (const float*)d_in[4];
  const float* WV = (const float*)d_in[5];
  const float* bias = (const float*)d_in[6];
  float* out = (float*)d_out;
  char* ws = (char*)d_ws;

  // byte offsets (16B aligned)
  const size_t oAQ = 0;                       // f32 [8192][8]   256 KB
  const size_t oAK = 262144;                  // f32 [8192][8]   256 KB
  const size_t oSA = 524288;                  // f32 [64][1024]  256 KB
  const size_t oSI = 786432;                  // i32 [64][1024]  256 KB
  const size_t oS1 = 1048576;                 // f32 [64][1025]  pad 288K
  const size_t oS2 = oS1 + 294912;
  const size_t oVP = oS2 + 294912;            // f16 [8192][512] 8 MB
  const size_t oU1 = oVP + 8388608;           // f16 [64][1025][64] ~8 MB
  const size_t oU2 = oU1 + 8396800;
  const size_t oCT1 = oU2 + 8396800;          // f32 [64][32][64] 512 KB
  const size_t oCT2 = oCT1 + 524288;
  const size_t oSC1 = oCT2 + 524288;          // f32 [64][32] 8 KB
  const size_t oSC2 = oSC1 + 8192;
  const size_t NEED_MAIN = oSC2 + 8192;       // ~27.7 MB
  const size_t NEED_FB = 524288 + 16777216;   // ~17 MB

  if (ws_size >= NEED_MAIN) {
    float* aQ = (float*)(ws + oAQ);
    float* aK = (float*)(ws + oAK);
    float* sA = (float*)(ws + oSA);
    int* sI = (int*)(ws + oSI);
    float* S1 = (float*)(ws + oS1);
    float* S2 = (float*)(ws + oS2);
    _Float16* Vp = (_Float16*)(ws + oVP);
    _Float16* U1 = (_Float16*)(ws + oU1);
    _Float16* U2 = (_Float16*)(ws + oU2);
    float* ct1 = (float*)(ws + oCT1);
    float* ct2 = (float*)(ws + oCT2);
    float* sc1 = (float*)(ws + oSC1);
    float* sc2 = (float*)(ws + oSC2);
    hipLaunchKernelGGL(projQK_kernel, dim3(4096), dim3(256), 0, stream, Q, K,
                       WQ, WK, aQ, aK);
    hipLaunchKernelGGL(sort_kernel, dim3(64), dim3(1024), 0, stream, aK, sA, sI);
    hipLaunchKernelGGL(vproj_mfma, dim3(64, 4), dim3(256), 0, stream, V, WV, Vp);
    hipLaunchKernelGGL(prefixA_kernel, dim3(512), dim3(256), 0, stream, sA, sI,
                       Vp, ct1, ct2, sc1, sc2);
    hipLaunchKernelGGL(prefixC_kernel, dim3(512), dim3(256), 0, stream, sA, sI,
                       Vp, ct1, ct2, sc1, sc2, U1, U2, S1, S2);
    hipLaunchKernelGGL(final_kernel, dim3(16384), dim3(256), 0, stream, aQ, sA,
                       U1, U2, S1, S2, bias, out);
  } else if (ws_size >= NEED_FB) {
    float* aQ = (float*)(ws + 0);
    float* aK = (float*)(ws + 262144);
    float* Vpf = (float*)(ws + 524288);
    hipLaunchKernelGGL(projQK_kernel, dim3(4096), dim3(256), 0, stream, Q, K,
                       WQ, WK, aQ, aK);
    hipLaunchKernelGGL(vproj_gemm, dim3(128, 8), dim3(256), 0, stream, V, WV,
                       Vpf);
    hipLaunchKernelGGL(direct_kernel, dim3(1024), dim3(256), 0, stream, aQ, aK,
                       Vpf, bias, out);
  }
}

// Round 5
// 93.147 us; speedup vs baseline: 1.2796x; 1.1849x over previous
//
#include <hip/hip_runtime.h>
#include <hip/hip_bf16.h>

#define NS 0.2f

// Problem sizes (fixed): B=8, S=1024, D=512, H=8, OD=64

typedef _Float16 half8 __attribute__((ext_vector_type(8)));
typedef float f32x4 __attribute__((ext_vector_type(4)));

// ---------------------------------------------------------------------------
// Fused Q/K projection: aX[row*8+h] = sum_d X[row][d]*W[h][d]
// blocks 0..2047 -> Q, 2048..4095 -> K. 4 waves/block, one row per wave.
// ---------------------------------------------------------------------------
__global__ __launch_bounds__(256) void projQK_kernel(
    const float* __restrict__ Q, const float* __restrict__ K,
    const float* __restrict__ WQ, const float* __restrict__ WK,
    float* __restrict__ aQ, float* __restrict__ aK) {
  int bid = blockIdx.x;
  const float* X;
  const float* W;
  float* aX;
  int rb;
  if (bid < 2048) { X = Q; W = WQ; aX = aQ; rb = bid; }
  else            { X = K; W = WK; aX = aK; rb = bid - 2048; }
  __shared__ __align__(16) float Wl[8 * 512];
  int t = threadIdx.x;
#pragma unroll
  for (int i = 0; i < 16; i++) Wl[i * 256 + t] = W[i * 256 + t];
  __syncthreads();
  int w = t >> 6, lane = t & 63;
  int row = rb * 4 + w;
  const float* x = X + (size_t)row * 512;
  float4 x0 = *(const float4*)(x + lane * 4);
  float4 x1 = *(const float4*)(x + 256 + lane * 4);
  float acc[8];
#pragma unroll
  for (int h = 0; h < 8; h++) {
    const float* wl = Wl + h * 512;
    float4 w0 = *(const float4*)(wl + lane * 4);
    float4 w1 = *(const float4*)(wl + 256 + lane * 4);
    float a = x0.x * w0.x + x0.y * w0.y + x0.z * w0.z + x0.w * w0.w +
              x1.x * w1.x + x1.y * w1.y + x1.z * w1.z + x1.w * w1.w;
#pragma unroll
    for (int off = 32; off > 0; off >>= 1) a += __shfl_xor(a, off);
    acc[h] = a;
  }
  if (lane == 0) {
    float* o = aX + (size_t)row * 8;
    o[0] = acc[0]; o[1] = acc[1]; o[2] = acc[2]; o[3] = acc[3];
    o[4] = acc[4]; o[5] = acc[5]; o[6] = acc[6]; o[7] = acc[7];
  }
}

// ---------------------------------------------------------------------------
// Vproj = V(8192x512) @ WV.T(512x512) -> f16 C(8192x512)
// R2-proven 64x64 tile, BK=32, grid 1024 (4 blocks/CU latency hiding).
// XOR-swizzled LDS: elem (r,k) at r*32 + ((k>>3) ^ ((r>>1)&3))*8 + (k&7)
// ---------------------------------------------------------------------------
__global__ __launch_bounds__(256) void vproj_mfma(
    const float* __restrict__ A, const float* __restrict__ Wv,
    _Float16* __restrict__ C) {
  __shared__ __align__(16) _Float16 As[64 * 32];
  __shared__ __align__(16) _Float16 Bs[64 * 32];
  int t = threadIdx.x;
  int m0 = blockIdx.x * 64, n0 = blockIdx.y * 64;
  int lane = t & 63, wid = t >> 6;
  int wr = wid >> 1, wc = wid & 1;
  int sr = t >> 2, sc = t & 3;
  const float* ap = A + (size_t)(m0 + sr) * 512 + sc * 8;
  const float* bp = Wv + (size_t)(n0 + sr) * 512 + sc * 8;
  _Float16* aw = As + sr * 32 + ((sc ^ ((sr >> 1) & 3)) * 8);
  _Float16* bw = Bs + sr * 32 + ((sc ^ ((sr >> 1) & 3)) * 8);
  int fr = lane & 15, fs = lane >> 4;
  f32x4 acc[2][2];
#pragma unroll
  for (int i = 0; i < 2; i++)
#pragma unroll
    for (int j = 0; j < 2; j++)
#pragma unroll
      for (int r = 0; r < 4; r++) acc[i][j][r] = 0.f;

  for (int k0 = 0; k0 < 512; k0 += 32) {
    float4 av0 = *(const float4*)(ap + k0);
    float4 av1 = *(const float4*)(ap + k0 + 4);
    float4 bv0 = *(const float4*)(bp + k0);
    float4 bv1 = *(const float4*)(bp + k0 + 4);
    __syncthreads();
    half8 ah, bh;
    ah[0] = (_Float16)av0.x; ah[1] = (_Float16)av0.y;
    ah[2] = (_Float16)av0.z; ah[3] = (_Float16)av0.w;
    ah[4] = (_Float16)av1.x; ah[5] = (_Float16)av1.y;
    ah[6] = (_Float16)av1.z; ah[7] = (_Float16)av1.w;
    bh[0] = (_Float16)bv0.x; bh[1] = (_Float16)bv0.y;
    bh[2] = (_Float16)bv0.z; bh[3] = (_Float16)bv0.w;
    bh[4] = (_Float16)bv1.x; bh[5] = (_Float16)bv1.y;
    bh[6] = (_Float16)bv1.z; bh[7] = (_Float16)bv1.w;
    *(half8*)aw = ah;
    *(half8*)bw = bh;
    __syncthreads();
    half8 af[2], bf[2];
#pragma unroll
    for (int i = 0; i < 2; i++) {
      int R = wr * 32 + i * 16 + fr;
      af[i] = *(half8*)(As + R * 32 + ((fs ^ ((R >> 1) & 3)) * 8));
    }
#pragma unroll
    for (int j = 0; j < 2; j++) {
      int Cc = wc * 32 + j * 16 + fr;
      bf[j] = *(half8*)(Bs + Cc * 32 + ((fs ^ ((Cc >> 1) & 3)) * 8));
    }
#pragma unroll
    for (int i = 0; i < 2; i++)
#pragma unroll
      for (int j = 0; j < 2; j++)
        acc[i][j] = __builtin_amdgcn_mfma_f32_16x16x32_f16(af[i], bf[j],
                                                           acc[i][j], 0, 0, 0);
  }
  // C/D layout (m89-verified): col = lane&15, row = (lane>>4)*4 + reg
#pragma unroll
  for (int i = 0; i < 2; i++)
#pragma unroll
    for (int j = 0; j < 2; j++) {
      int row = m0 + wr * 32 + i * 16 + fs * 4;
      int col = n0 + wc * 32 + j * 16 + fr;
#pragma unroll
      for (int r = 0; r < 4; r++)
        C[(size_t)(row + r) * 512 + col] = (_Float16)acc[i][j][r];
    }
}

// ---------------------------------------------------------------------------
// Fused per-(b,h) kernel (grid 64, block 1024):
//  1) bitonic sort of aK column (keys in LDS at end)
//  2) E1/E2/IDX (max-subtracted exps) -> global
//  3) 32 chunk totals over gathered e*Vp -> exclusive chunk scans (cofs) +
//     scalar analogs (scof) -> global
//  4) query binning: in-LDS binary search per query, histogram+scan+scatter
// ---------------------------------------------------------------------------
__global__ __launch_bounds__(1024) void sortbin_kernel(
    const float* __restrict__ aK, const float* __restrict__ aQ,
    const _Float16* __restrict__ Vp, float* __restrict__ E1g,
    float* __restrict__ E2g, int* __restrict__ IDXg,
    float* __restrict__ cofs1, float* __restrict__ cofs2,
    float* __restrict__ scof1, float* __restrict__ scof2,
    float* __restrict__ amaxArr, int* __restrict__ binStart,
    int* __restrict__ binData, float* __restrict__ binX) {
  int bh = blockIdx.x, b = bh >> 3, h = bh & 7;
  __shared__ float key[1024];
  __shared__ int idx[1024];
  __shared__ float E1s[1024], E2s[1024];
  __shared__ float ct1[32][64], ct2[32][64];
  __shared__ float sct1[32], sct2[32];
  __shared__ int cnt[32], bstart[33];
  int t = threadIdx.x;
  // ---- 1) bitonic sort (register + LDS hybrid) ----
  float k = aK[(size_t)(b * 1024 + t) * 8 + h];
  int id = t;
  for (int len = 2; len <= 1024; len <<= 1) {
    bool up = ((t & len) == 0);
    for (int stride = len >> 1; stride >= 64; stride >>= 1) {
      key[t] = k; idx[t] = id;
      __syncthreads();
      int p = t ^ stride;
      float k2 = key[p];
      int i2 = idx[p];
      __syncthreads();
      bool takeMin = (((t & stride) == 0) == up);
      bool take2 = takeMin ? (k2 < k) : (k2 > k);
      if (take2) { k = k2; id = i2; }
    }
    int s0 = (len >> 1) < 32 ? (len >> 1) : 32;
    for (int stride = s0; stride >= 1; stride >>= 1) {
      float k2 = __shfl_xor(k, stride);
      int i2 = __shfl_xor(id, stride);
      bool takeMin = (((t & stride) == 0) == up);
      bool take2 = takeMin ? (k2 < k) : (k2 > k);
      if (take2) { k = k2; id = i2; }
    }
  }
  key[t] = k; idx[t] = id;
  __syncthreads();
  // ---- 2) exps ----
  float amax = key[1023];
  float e1 = __expf(k - amax);
  float e2 = __expf(NS * (k - amax));
  E1s[t] = e1; E2s[t] = e2;
  E1g[bh * 1024 + t] = e1;
  E2g[bh * 1024 + t] = e2;
  IDXg[bh * 1024 + t] = id;
  if (t == 0) amaxArr[bh] = amax;
  __syncthreads();
  // ---- 3) chunk totals (32 chunks x 32 keys), thread (cgrp,d) ----
  {
    int d = t & 63;
    const _Float16* vb = Vp + (size_t)b * 1024 * 512 + h * 64 + d;
    for (int cc = t >> 6; cc < 32; cc += 16) {
      float t1 = 0.f, t2 = 0.f;
#pragma unroll 8
      for (int j = 0; j < 32; j++) {
        int i = cc * 32 + j;
        float v = (float)vb[(size_t)idx[i] * 512];
        t1 += E1s[i] * v;
        t2 += E2s[i] * v;
      }
      ct1[cc][d] = t1; ct2[cc][d] = t2;
    }
    if (t < 32) {
      float s1 = 0.f, s2 = 0.f;
      for (int j = 0; j < 32; j++) { s1 += E1s[t * 32 + j]; s2 += E2s[t * 32 + j]; }
      sct1[t] = s1; sct2[t] = s2;
    }
  }
  __syncthreads();
  // exclusive chunk scans -> cofs (suffix for e1, prefix for e2)
  {
    int d = t & 63;
    for (int cc = t >> 6; cc < 32; cc += 16) {
      float o1 = 0.f, o2 = 0.f;
      for (int kk = cc + 1; kk < 32; kk++) o1 += ct1[kk][d];
      for (int kk = 0; kk < cc; kk++) o2 += ct2[kk][d];
      cofs1[(bh * 32 + cc) * 64 + d] = o1;
      cofs2[(bh * 32 + cc) * 64 + d] = o2;
    }
    if (t < 32) {
      float o1 = 0.f, o2 = 0.f;
      for (int kk = t + 1; kk < 32; kk++) o1 += sct1[kk];
      for (int kk = 0; kk < t; kk++) o2 += sct2[kk];
      scof1[bh * 32 + t] = o1;
      scof2[bh * 32 + t] = o2;
    }
  }
  // ---- 4) query binning ----
  float x = aQ[(size_t)(b * 1024 + t) * 8 + h];
  float negx = -x;
  int lo = 0, hi = 1024;
  while (lo < hi) {
    int mid = (lo + hi) >> 1;
    if (key[mid] <= negx) lo = mid + 1; else hi = mid;
  }
  int ix = lo;
  int c = ix >> 5; if (c > 31) c = 31;
  if (t < 32) cnt[t] = 0;
  __syncthreads();
  int slot = atomicAdd(&cnt[c], 1);
  __syncthreads();
  if (t == 0) {
    int s = 0;
    for (int i = 0; i < 32; i++) { bstart[i] = s; s += cnt[i]; }
    bstart[32] = s;
  }
  __syncthreads();
  if (t < 33) binStart[bh * 33 + t] = bstart[t];
  int pos = bstart[c] + slot;
  binData[bh * 1024 + pos] = (t << 11) | ix;
  binX[bh * 1024 + pos] = x;
}

// ---------------------------------------------------------------------------
// final: grid 2048 = bh*32 + chunk. Block loads chunk's 32 e*Vp rows into
// LDS, coarse offsets from cofs/scof, then answers each binned query with a
// 32-step masked in-LDS sum. No U arrays in HBM.
// ---------------------------------------------------------------------------
__global__ __launch_bounds__(256) void final_binned(
    const float* __restrict__ E1g, const float* __restrict__ E2g,
    const int* __restrict__ IDXg, const _Float16* __restrict__ Vp,
    const float* __restrict__ cofs1, const float* __restrict__ cofs2,
    const float* __restrict__ scof1, const float* __restrict__ scof2,
    const float* __restrict__ amaxArr, const int* __restrict__ binStart,
    const int* __restrict__ binData, const float* __restrict__ binX,
    const float* __restrict__ aQ, const float* __restrict__ bias,
    float* __restrict__ out) {
  int blk = blockIdx.x;
  int bh = blk >> 5, c = blk & 31;
  int b = bh >> 3, h = bh & 7;
  int t = threadIdx.x, w = t >> 6, lane = t & 63;
  __shared__ float ev1[32][64], ev2[32][64];
  __shared__ float sS1[33], sS2[33];
  __shared__ float e1c[32], e2c[32];
  int n0 = binStart[bh * 33 + c];
  int n = binStart[bh * 33 + c + 1] - n0;
  if (n == 0) return;
  if (t < 32) {
    e1c[t] = E1g[bh * 1024 + c * 32 + t];
    e2c[t] = E2g[bh * 1024 + c * 32 + t];
  }
  __syncthreads();
  {
    const _Float16* vb = Vp + (size_t)b * 1024 * 512 + h * 64 + lane;
#pragma unroll
    for (int j = w * 8; j < w * 8 + 8; j++) {
      int row = IDXg[bh * 1024 + c * 32 + j];
      float v = (float)vb[(size_t)row * 512];
      ev1[j][lane] = e1c[j] * v;
      ev2[j][lane] = e2c[j] * v;
    }
  }
  if (t == 0) {
    float s = 0.f;
    sS1[32] = 0.f;
    for (int l = 31; l >= 0; l--) { s += e1c[l]; sS1[l] = s; }
    s = 0.f;
    sS2[0] = 0.f;
    for (int l = 1; l <= 32; l++) { s += e2c[l - 1]; sS2[l] = s; }
  }
  float o1 = cofs1[(bh * 32 + c) * 64 + lane];
  float o2 = cofs2[(bh * 32 + c) * 64 + lane];
  float so1 = scof1[bh * 32 + c];
  float so2 = scof2[bh * 32 + c];
  float amax = amaxArr[bh];
  float bi = bias[h * 64 + lane];
  __syncthreads();
  for (int qi = w; qi < n; qi += 4) {
    int rec = binData[bh * 1024 + n0 + qi];
    float x = binX[bh * 1024 + n0 + qi];
    int q = rec >> 11;
    int ix = rec & 2047;
    int l = ix - c * 32;  // in [0,32]
    float num1 = o1, num2 = o2;
#pragma unroll
    for (int j = 0; j < 32; j++) {
      bool suf = (j >= l);
      num1 += suf ? ev1[j][lane] : 0.f;
      num2 += suf ? 0.f : ev2[j][lane];
    }
    float xs = x + amax;
    float ex = __expf(xs), e2x = __expf(NS * xs);
    float Z = ex * (so1 + sS1[l]) + e2x * (so2 + sS2[l]);
    out[((size_t)(b * 1024 + q)) * 512 + h * 64 + lane] =
        (ex * num1 + e2x * num2) / Z + bi;
  }
}

// ---------------------------------------------------------------------------
// Fallback path kernels (small ws): f32 GEMM + direct attention
// ---------------------------------------------------------------------------
__global__ __launch_bounds__(256) void vproj_gemm(
    const float* __restrict__ A, const float* __restrict__ Wv,
    float* __restrict__ C) {
  __shared__ __align__(16) float As[16][68];
  __shared__ __align__(16) float Bs[16][68];
  int t = threadIdx.x;
  int m0 = blockIdx.x * 64, n0 = blockIdx.y * 64;
  int tx = t & 15, ty = t >> 4;
  int lr = t >> 2, lk = (t & 3) * 4;
  float acc[4][4] = {{0.f}};
  const float* ap = A + (size_t)(m0 + lr) * 512 + lk;
  const float* bp = Wv + (size_t)(n0 + lr) * 512 + lk;
  for (int k0 = 0; k0 < 512; k0 += 16) {
    float4 av = *(const float4*)(ap + k0);
    float4 bv = *(const float4*)(bp + k0);
    __syncthreads();
    As[lk + 0][lr] = av.x; As[lk + 1][lr] = av.y;
    As[lk + 2][lr] = av.z; As[lk + 3][lr] = av.w;
    Bs[lk + 0][lr] = bv.x; Bs[lk + 1][lr] = bv.y;
    Bs[lk + 2][lr] = bv.z; Bs[lk + 3][lr] = bv.w;
    __syncthreads();
#pragma unroll
    for (int kk = 0; kk < 16; kk++) {
      float4 a4 = *(const float4*)&As[kk][ty * 4];
      float4 b4 = *(const float4*)&Bs[kk][tx * 4];
      float aa[4] = {a4.x, a4.y, a4.z, a4.w};
      float bb[4] = {b4.x, b4.y, b4.z, b4.w};
#pragma unroll
      for (int i = 0; i < 4; i++)
#pragma unroll
        for (int j = 0; j < 4; j++) acc[i][j] += aa[i] * bb[j];
    }
  }
#pragma unroll
  for (int i = 0; i < 4; i++) {
    float4 o = {acc[i][0], acc[i][1], acc[i][2], acc[i][3]};
    *(float4*)(C + (size_t)(m0 + ty * 4 + i) * 512 + n0 + tx * 4) = o;
  }
}

__global__ __launch_bounds__(256) void direct_kernel(
    const float* __restrict__ aQ, const float* __restrict__ aK,
    const float* __restrict__ Vp, const float* __restrict__ bias,
    float* __restrict__ out) {
  int id = blockIdx.x;
  int qt = id & 15, h = (id >> 4) & 7, b = id >> 7;
  __shared__ float AK[1024], E1s[1024], E2s[1024];
  __shared__ __align__(16) float VT[128][64];
  __shared__ float XQ[64];
  int t = threadIdx.x;
  for (int i = t; i < 1024; i += 256) {
    float a = aK[(size_t)(b * 1024 + i) * 8 + h];
    AK[i] = a; E1s[i] = __expf(a); E2s[i] = __expf(NS * a);
  }
  if (t < 64) XQ[t] = aQ[(size_t)(b * 1024 + qt * 64 + t) * 8 + h];
  __syncthreads();
  int w = t >> 6, d = t & 63;
  float xq[16], ex[16], e2x[16], acc[16], z[16];
#pragma unroll
  for (int qi = 0; qi < 16; qi++) {
    float x = XQ[w * 16 + qi];
    xq[qi] = x; ex[qi] = __expf(x); e2x[qi] = __expf(NS * x);
    acc[qi] = 0.f; z[qi] = 0.f;
  }
  for (int kt = 0; kt < 8; kt++) {
    __syncthreads();
    for (int i = t; i < 128 * 64; i += 256) {
      VT[i >> 6][i & 63] =
          Vp[(size_t)(b * 1024 + kt * 128 + (i >> 6)) * 512 + h * 64 + (i & 63)];
    }
    __syncthreads();
    for (int kk = 0; kk < 128; kk++) {
      int k = kt * 128 + kk;
      float a = AK[k], e1 = E1s[k], e2 = E2s[k];
      float v = VT[kk][d];
#pragma unroll
      for (int qi = 0; qi < 16; qi++) {
        float wsel = (a + xq[qi] > 0.f) ? (ex[qi] * e1) : (e2x[qi] * e2);
        acc[qi] += wsel * v;
        z[qi] += wsel;
      }
    }
  }
#pragma unroll
  for (int qi = 0; qi < 16; qi++) {
    int q = qt * 64 + w * 16 + qi;
    out[(size_t)(b * 1024 + q) * 512 + h * 64 + d] =
        acc[qi] / z[qi] + bias[h * 64 + d];
  }
}

// ---------------------------------------------------------------------------
extern "C" void kernel_launch(void* const* d_in, const int* in_sizes, int n_in,
                              void* d_out, int out_size, void* d_ws,
                              size_t ws_size, hipStream_t stream) {
  const float* Q = (const float*)d_in[0];
  const float* K = (const float*)d_in[1];
  const float* V = (const float*)d_in[2];
  const float* WQ = (const float*)d_in[3];
  const float* WK = (const float*)d_in[4];
  const float* WV = (const float*)d_in[5];
  const float* bias = (const float*)d_in[6];
  float* out = (float*)d_out;
  char* ws = (char*)d_ws;

  // byte offsets (16B aligned)
  const size_t oAQ   = 0;                   // f32 [8192][8]      256 KB
  const size_t oAK   = 262144;              // f32 [8192][8]      256 KB
  const size_t oE1   = 524288;              // f32 [64][1024]     256 KB
  const size_t oE2   = 786432;              // f32 [64][1024]     256 KB
  const size_t oIDX  = 1048576;             // i32 [64][1024]     256 KB
  const size_t oCOF1 = 1310720;             // f32 [64][32][64]   512 KB
  const size_t oCOF2 = 1835008;             // f32 [64][32][64]   512 KB
  const size_t oSC1  = 2359296;             // f32 [64][32]  (pad 16K)
  const size_t oSC2  = 2375680;
  const size_t oAMX  = 2392064;             // f32 [64]      (pad 4K)
  const size_t oBST  = 2396160;             // i32 [64][33]  (pad 16K)
  const size_t oBDA  = 2412544;             // i32 [64][1024]     256 KB
  const size_t oBX   = 2674688;             // f32 [64][1024]     256 KB
  const size_t oVP   = 2936832;             // f16 [8192][512]    8 MB
  const size_t NEED_MAIN = oVP + 8388608;   // ~10.8 MB
  const size_t NEED_FB = 524288 + 16777216; // ~17 MB

  if (ws_size >= NEED_MAIN) {
    float* aQ = (float*)(ws + oAQ);
    float* aK = (float*)(ws + oAK);
    float* E1g = (float*)(ws + oE1);
    float* E2g = (float*)(ws + oE2);
    int* IDXg = (int*)(ws + oIDX);
    float* cofs1 = (float*)(ws + oCOF1);
    float* cofs2 = (float*)(ws + oCOF2);
    float* scof1 = (float*)(ws + oSC1);
    float* scof2 = (float*)(ws + oSC2);
    float* amaxA = (float*)(ws + oAMX);
    int* binSt = (int*)(ws + oBST);
    int* binDa = (int*)(ws + oBDA);
    float* binX = (float*)(ws + oBX);
    _Float16* Vp = (_Float16*)(ws + oVP);
    hipLaunchKernelGGL(projQK_kernel, dim3(4096), dim3(256), 0, stream, Q, K,
                       WQ, WK, aQ, aK);
    hipLaunchKernelGGL(vproj_mfma, dim3(128, 8), dim3(256), 0, stream, V, WV,
                       Vp);
    hipLaunchKernelGGL(sortbin_kernel, dim3(64), dim3(1024), 0, stream, aK, aQ,
                       Vp, E1g, E2g, IDXg, cofs1, cofs2, scof1, scof2, amaxA,
                       binSt, binDa, binX);
    hipLaunchKernelGGL(final_binned, dim3(2048), dim3(256), 0, stream, E1g,
                       E2g, IDXg, Vp, cofs1, cofs2, scof1, scof2, amaxA, binSt,
                       binDa, binX, aQ, bias, out);
  } else if (ws_size >= NEED_FB) {
    float* aQ = (float*)(ws + 0);
    float* aK = (float*)(ws + 262144);
    float* Vpf = (float*)(ws + 524288);
    hipLaunchKernelGGL(projQK_kernel, dim3(4096), dim3(256), 0, stream, Q, K,
                       WQ, WK, aQ, aK);
    hipLaunchKernelGGL(vproj_gemm, dim3(128, 8), dim3(256), 0, stream, V, WV,
                       Vpf);
    hipLaunchKernelGGL(direct_kernel, dim3(1024), dim3(256), 0, stream, aQ, aK,
                       Vpf, bias, out);
  }
}

// Round 6
// 68.453 us; speedup vs baseline: 1.7412x; 1.3607x over previous
//
#include <hip/hip_runtime.h>
#include <hip/hip_bf16.h>

#define NS 0.2f

// Problem sizes (fixed): B=8, S=1024, D=512, H=8, OD=64

typedef _Float16 half8 __attribute__((ext_vector_type(8)));
typedef float f32x4 __attribute__((ext_vector_type(4)));

// ---------------------------------------------------------------------------
// Fused Q/K projection: aX[row*8+h] = sum_d X[row][d]*W[h][d]
// blocks 0..2047 -> Q, 2048..4095 -> K. 4 waves/block, one row per wave.
// ---------------------------------------------------------------------------
__global__ __launch_bounds__(256) void projQK_kernel(
    const float* __restrict__ Q, const float* __restrict__ K,
    const float* __restrict__ WQ, const float* __restrict__ WK,
    float* __restrict__ aQ, float* __restrict__ aK) {
  int bid = blockIdx.x;
  const float* X;
  const float* W;
  float* aX;
  int rb;
  if (bid < 2048) { X = Q; W = WQ; aX = aQ; rb = bid; }
  else            { X = K; W = WK; aX = aK; rb = bid - 2048; }
  __shared__ __align__(16) float Wl[8 * 512];
  int t = threadIdx.x;
#pragma unroll
  for (int i = 0; i < 16; i++) Wl[i * 256 + t] = W[i * 256 + t];
  __syncthreads();
  int w = t >> 6, lane = t & 63;
  int row = rb * 4 + w;
  const float* x = X + (size_t)row * 512;
  float4 x0 = *(const float4*)(x + lane * 4);
  float4 x1 = *(const float4*)(x + 256 + lane * 4);
  float acc[8];
#pragma unroll
  for (int h = 0; h < 8; h++) {
    const float* wl = Wl + h * 512;
    float4 w0 = *(const float4*)(wl + lane * 4);
    float4 w1 = *(const float4*)(wl + 256 + lane * 4);
    float a = x0.x * w0.x + x0.y * w0.y + x0.z * w0.z + x0.w * w0.w +
              x1.x * w1.x + x1.y * w1.y + x1.z * w1.z + x1.w * w1.w;
#pragma unroll
    for (int off = 32; off > 0; off >>= 1) a += __shfl_xor(a, off);
    acc[h] = a;
  }
  if (lane == 0) {
    float* o = aX + (size_t)row * 8;
    o[0] = acc[0]; o[1] = acc[1]; o[2] = acc[2]; o[3] = acc[3];
    o[4] = acc[4]; o[5] = acc[5]; o[6] = acc[6]; o[7] = acc[7];
  }
}

// ---------------------------------------------------------------------------
// Vproj = V(8192x512) @ WV.T(512x512) -> f16 C(8192x512)
// R2-proven 64x64 tile, BK=32, grid 1024 (4 blocks/CU latency hiding).
// XOR-swizzled LDS: elem (r,k) at r*32 + ((k>>3) ^ ((r>>1)&3))*8 + (k&7)
// ---------------------------------------------------------------------------
__global__ __launch_bounds__(256) void vproj_mfma(
    const float* __restrict__ A, const float* __restrict__ Wv,
    _Float16* __restrict__ C) {
  __shared__ __align__(16) _Float16 As[64 * 32];
  __shared__ __align__(16) _Float16 Bs[64 * 32];
  int t = threadIdx.x;
  int m0 = blockIdx.x * 64, n0 = blockIdx.y * 64;
  int lane = t & 63, wid = t >> 6;
  int wr = wid >> 1, wc = wid & 1;
  int sr = t >> 2, sc = t & 3;
  const float* ap = A + (size_t)(m0 + sr) * 512 + sc * 8;
  const float* bp = Wv + (size_t)(n0 + sr) * 512 + sc * 8;
  _Float16* aw = As + sr * 32 + ((sc ^ ((sr >> 1) & 3)) * 8);
  _Float16* bw = Bs + sr * 32 + ((sc ^ ((sr >> 1) & 3)) * 8);
  int fr = lane & 15, fs = lane >> 4;
  f32x4 acc[2][2];
#pragma unroll
  for (int i = 0; i < 2; i++)
#pragma unroll
    for (int j = 0; j < 2; j++)
#pragma unroll
      for (int r = 0; r < 4; r++) acc[i][j][r] = 0.f;

  for (int k0 = 0; k0 < 512; k0 += 32) {
    float4 av0 = *(const float4*)(ap + k0);
    float4 av1 = *(const float4*)(ap + k0 + 4);
    float4 bv0 = *(const float4*)(bp + k0);
    float4 bv1 = *(const float4*)(bp + k0 + 4);
    __syncthreads();
    half8 ah, bh;
    ah[0] = (_Float16)av0.x; ah[1] = (_Float16)av0.y;
    ah[2] = (_Float16)av0.z; ah[3] = (_Float16)av0.w;
    ah[4] = (_Float16)av1.x; ah[5] = (_Float16)av1.y;
    ah[6] = (_Float16)av1.z; ah[7] = (_Float16)av1.w;
    bh[0] = (_Float16)bv0.x; bh[1] = (_Float16)bv0.y;
    bh[2] = (_Float16)bv0.z; bh[3] = (_Float16)bv0.w;
    bh[4] = (_Float16)bv1.x; bh[5] = (_Float16)bv1.y;
    bh[6] = (_Float16)bv1.z; bh[7] = (_Float16)bv1.w;
    *(half8*)aw = ah;
    *(half8*)bw = bh;
    __syncthreads();
    half8 af[2], bf[2];
#pragma unroll
    for (int i = 0; i < 2; i++) {
      int R = wr * 32 + i * 16 + fr;
      af[i] = *(half8*)(As + R * 32 + ((fs ^ ((R >> 1) & 3)) * 8));
    }
#pragma unroll
    for (int j = 0; j < 2; j++) {
      int Cc = wc * 32 + j * 16 + fr;
      bf[j] = *(half8*)(Bs + Cc * 32 + ((fs ^ ((Cc >> 1) & 3)) * 8));
    }
#pragma unroll
    for (int i = 0; i < 2; i++)
#pragma unroll
      for (int j = 0; j < 2; j++)
        acc[i][j] = __builtin_amdgcn_mfma_f32_16x16x32_f16(af[i], bf[j],
                                                           acc[i][j], 0, 0, 0);
  }
  // C/D layout (m89-verified): col = lane&15, row = (lane>>4)*4 + reg
#pragma unroll
  for (int i = 0; i < 2; i++)
#pragma unroll
    for (int j = 0; j < 2; j++) {
      int row = m0 + wr * 32 + i * 16 + fs * 4;
      int col = n0 + wc * 32 + j * 16 + fr;
#pragma unroll
      for (int r = 0; r < 4; r++)
        C[(size_t)(row + r) * 512 + col] = (_Float16)acc[i][j][r];
    }
}

// ---------------------------------------------------------------------------
// Fused per-(b,h) kernel (grid 64, block 1024):
//  1) bitonic sort of aK column (keys in LDS at end)
//  2) E1/E2/IDX (max-subtracted exps) -> global
//  3) 32 chunk totals over gathered e*Vp -> exclusive chunk scans (cofs) +
//     scalar analogs (scof) -> global
//  4) query binning: in-LDS binary search per query, histogram+scan+scatter
// ---------------------------------------------------------------------------
__global__ __launch_bounds__(1024) void sortbin_kernel(
    const float* __restrict__ aK, const float* __restrict__ aQ,
    const _Float16* __restrict__ Vp, float* __restrict__ E1g,
    float* __restrict__ E2g, int* __restrict__ IDXg,
    float* __restrict__ cofs1, float* __restrict__ cofs2,
    float* __restrict__ scof1, float* __restrict__ scof2,
    float* __restrict__ amaxArr, int* __restrict__ binStart,
    int* __restrict__ binData, float* __restrict__ binX) {
  int bh = blockIdx.x, b = bh >> 3, h = bh & 7;
  __shared__ float key[1024];
  __shared__ int idx[1024];
  __shared__ float E1s[1024], E2s[1024];
  __shared__ float ct1[32][64], ct2[32][64];
  __shared__ float sct1[32], sct2[32];
  __shared__ int cnt[32], bstart[33];
  int t = threadIdx.x;
  // ---- 1) bitonic sort (register + LDS hybrid) ----
  float k = aK[(size_t)(b * 1024 + t) * 8 + h];
  int id = t;
  for (int len = 2; len <= 1024; len <<= 1) {
    bool up = ((t & len) == 0);
    for (int stride = len >> 1; stride >= 64; stride >>= 1) {
      key[t] = k; idx[t] = id;
      __syncthreads();
      int p = t ^ stride;
      float k2 = key[p];
      int i2 = idx[p];
      __syncthreads();
      bool takeMin = (((t & stride) == 0) == up);
      bool take2 = takeMin ? (k2 < k) : (k2 > k);
      if (take2) { k = k2; id = i2; }
    }
    int s0 = (len >> 1) < 32 ? (len >> 1) : 32;
    for (int stride = s0; stride >= 1; stride >>= 1) {
      float k2 = __shfl_xor(k, stride);
      int i2 = __shfl_xor(id, stride);
      bool takeMin = (((t & stride) == 0) == up);
      bool take2 = takeMin ? (k2 < k) : (k2 > k);
      if (take2) { k = k2; id = i2; }
    }
  }
  key[t] = k; idx[t] = id;
  __syncthreads();
  // ---- 2) exps ----
  float amax = key[1023];
  float e1 = __expf(k - amax);
  float e2 = __expf(NS * (k - amax));
  E1s[t] = e1; E2s[t] = e2;
  E1g[bh * 1024 + t] = e1;
  E2g[bh * 1024 + t] = e2;
  IDXg[bh * 1024 + t] = id;
  if (t == 0) amaxArr[bh] = amax;
  __syncthreads();
  // ---- 3) chunk totals (32 chunks x 32 keys), thread (cgrp,d) ----
  {
    int d = t & 63;
    const _Float16* vb = Vp + (size_t)b * 1024 * 512 + h * 64 + d;
    for (int cc = t >> 6; cc < 32; cc += 16) {
      float t1 = 0.f, t2 = 0.f;
#pragma unroll 8
      for (int j = 0; j < 32; j++) {
        int i = cc * 32 + j;
        float v = (float)vb[(size_t)idx[i] * 512];
        t1 += E1s[i] * v;
        t2 += E2s[i] * v;
      }
      ct1[cc][d] = t1; ct2[cc][d] = t2;
    }
    if (t < 32) {
      float s1 = 0.f, s2 = 0.f;
      for (int j = 0; j < 32; j++) { s1 += E1s[t * 32 + j]; s2 += E2s[t * 32 + j]; }
      sct1[t] = s1; sct2[t] = s2;
    }
  }
  __syncthreads();
  // exclusive chunk scans -> cofs (suffix for e1, prefix for e2)
  {
    int d = t & 63;
    for (int cc = t >> 6; cc < 32; cc += 16) {
      float o1 = 0.f, o2 = 0.f;
      for (int kk = cc + 1; kk < 32; kk++) o1 += ct1[kk][d];
      for (int kk = 0; kk < cc; kk++) o2 += ct2[kk][d];
      cofs1[(bh * 32 + cc) * 64 + d] = o1;
      cofs2[(bh * 32 + cc) * 64 + d] = o2;
    }
    if (t < 32) {
      float o1 = 0.f, o2 = 0.f;
      for (int kk = t + 1; kk < 32; kk++) o1 += sct1[kk];
      for (int kk = 0; kk < t; kk++) o2 += sct2[kk];
      scof1[bh * 32 + t] = o1;
      scof2[bh * 32 + t] = o2;
    }
  }
  // ---- 4) query binning ----
  float x = aQ[(size_t)(b * 1024 + t) * 8 + h];
  float negx = -x;
  int lo = 0, hi = 1024;
  while (lo < hi) {
    int mid = (lo + hi) >> 1;
    if (key[mid] <= negx) lo = mid + 1; else hi = mid;
  }
  int ix = lo;
  int c = ix >> 5; if (c > 31) c = 31;
  if (t < 32) cnt[t] = 0;
  __syncthreads();
  int slot = atomicAdd(&cnt[c], 1);
  __syncthreads();
  if (t == 0) {
    int s = 0;
    for (int i = 0; i < 32; i++) { bstart[i] = s; s += cnt[i]; }
    bstart[32] = s;
  }
  __syncthreads();
  if (t < 33) binStart[bh * 33 + t] = bstart[t];
  int pos = bstart[c] + slot;
  binData[bh * 1024 + pos] = (t << 11) | ix;
  binX[bh * 1024 + pos] = x;
}

// ---------------------------------------------------------------------------
// final: grid 2048 = bh*32 + chunk. Per block: gather chunk's 32 Vp rows
// into registers (8/wave), build in-LDS prefix tables
//   P1[l][d] = sum_{j>=l} e1_j v_j[d]   (suffix, 33 entries)
//   P2[l][d] = sum_{j<l}  e2_j v_j[d]   (prefix, 33 entries)
// via register scans + cross-wave offset exchange. Each query then costs
// 2 LDS reads (vs 64 in the masked-sum version -> was LDS-throughput bound).
// ---------------------------------------------------------------------------
__global__ __launch_bounds__(256) void final_binned(
    const float* __restrict__ E1g, const float* __restrict__ E2g,
    const int* __restrict__ IDXg, const _Float16* __restrict__ Vp,
    const float* __restrict__ cofs1, const float* __restrict__ cofs2,
    const float* __restrict__ scof1, const float* __restrict__ scof2,
    const float* __restrict__ amaxArr, const int* __restrict__ binStart,
    const int* __restrict__ binData, const float* __restrict__ binX,
    const float* __restrict__ aQ, const float* __restrict__ bias,
    float* __restrict__ out) {
  int blk = blockIdx.x;
  int bh = blk >> 5, c = blk & 31;
  int b = bh >> 3, h = bh & 7;
  int t = threadIdx.x, w = t >> 6, lane = t & 63;
  __shared__ float P1[33][64], P2[33][64];
  __shared__ float G1s[4][64], G2s[4][64];
  __shared__ float sS1[33], sS2[33];
  __shared__ float e1c[32], e2c[32];
  int n0 = binStart[bh * 33 + c];
  int n = binStart[bh * 33 + c + 1] - n0;
  if (n == 0) return;
  if (t < 32) {
    e1c[t] = E1g[bh * 1024 + c * 32 + t];
    e2c[t] = E2g[bh * 1024 + c * 32 + t];
  }
  __syncthreads();
  // gather 8 rows per wave into registers, scale by e1/e2
  float f1[8], f2[8];
  {
    const _Float16* vb = Vp + (size_t)b * 1024 * 512 + h * 64 + lane;
    const int* ib = IDXg + bh * 1024 + c * 32 + w * 8;
#pragma unroll
    for (int k2 = 0; k2 < 8; k2++) {
      float v = (float)vb[(size_t)ib[k2] * 512];
      f1[k2] = e1c[w * 8 + k2] * v;
      f2[k2] = e2c[w * 8 + k2] * v;
    }
  }
  float G1 = 0.f, G2 = 0.f;
#pragma unroll
  for (int k2 = 0; k2 < 8; k2++) { G1 += f1[k2]; G2 += f2[k2]; }
  G1s[w][lane] = G1;
  G2s[w][lane] = G2;
  // scalar within-chunk scans (thread 0, while others reach barrier)
  if (t == 0) {
    float s = 0.f;
    sS1[32] = 0.f;
    for (int l = 31; l >= 0; l--) { s += e1c[l]; sS1[l] = s; }
    s = 0.f;
    sS2[0] = 0.f;
    for (int l = 1; l <= 32; l++) { s += e2c[l - 1]; sS2[l] = s; }
  }
  __syncthreads();
  // cross-wave offsets
  float off1 = 0.f, off2 = 0.f;
#pragma unroll
  for (int w2 = 0; w2 < 4; w2++) {
    float g1 = G1s[w2][lane], g2 = G2s[w2][lane];
    if (w2 > w) off1 += g1;
    if (w2 < w) off2 += g2;
  }
  // emit P1 (suffix) / P2 (exclusive prefix) rows 8w..8w+7 (+ boundaries)
  {
    float p1v[8];
    float s = 0.f;
#pragma unroll
    for (int k2 = 7; k2 >= 0; k2--) { s += f1[k2]; p1v[k2] = s; }
#pragma unroll
    for (int k2 = 0; k2 < 8; k2++) P1[w * 8 + k2][lane] = off1 + p1v[k2];
    float p = 0.f;
#pragma unroll
    for (int k2 = 0; k2 < 8; k2++) { P2[w * 8 + k2][lane] = off2 + p; p += f2[k2]; }
    if (w == 3) P2[32][lane] = off2 + p;
    if (w == 0) P1[32][lane] = 0.f;
  }
  float o1 = cofs1[(bh * 32 + c) * 64 + lane];
  float o2 = cofs2[(bh * 32 + c) * 64 + lane];
  float so1 = scof1[bh * 32 + c];
  float so2 = scof2[bh * 32 + c];
  float amax = amaxArr[bh];
  float bi = bias[h * 64 + lane];
  __syncthreads();
  for (int qi = w; qi < n; qi += 4) {
    int rec = binData[bh * 1024 + n0 + qi];
    float x = binX[bh * 1024 + n0 + qi];
    int q = rec >> 11;
    int l = (rec & 2047) - c * 32;  // in [0,32]
    float num1 = o1 + P1[l][lane];
    float num2 = o2 + P2[l][lane];
    float xs = x + amax;
    float ex = __expf(xs), e2x = __expf(NS * xs);
    float Z = ex * (so1 + sS1[l]) + e2x * (so2 + sS2[l]);
    out[((size_t)(b * 1024 + q)) * 512 + h * 64 + lane] =
        (ex * num1 + e2x * num2) / Z + bi;
  }
}

// ---------------------------------------------------------------------------
// Fallback path kernels (small ws): f32 GEMM + direct attention
// ---------------------------------------------------------------------------
__global__ __launch_bounds__(256) void vproj_gemm(
    const float* __restrict__ A, const float* __restrict__ Wv,
    float* __restrict__ C) {
  __shared__ __align__(16) float As[16][68];
  __shared__ __align__(16) float Bs[16][68];
  int t = threadIdx.x;
  int m0 = blockIdx.x * 64, n0 = blockIdx.y * 64;
  int tx = t & 15, ty = t >> 4;
  int lr = t >> 2, lk = (t & 3) * 4;
  float acc[4][4] = {{0.f}};
  const float* ap = A + (size_t)(m0 + lr) * 512 + lk;
  const float* bp = Wv + (size_t)(n0 + lr) * 512 + lk;
  for (int k0 = 0; k0 < 512; k0 += 16) {
    float4 av = *(const float4*)(ap + k0);
    float4 bv = *(const float4*)(bp + k0);
    __syncthreads();
    As[lk + 0][lr] = av.x; As[lk + 1][lr] = av.y;
    As[lk + 2][lr] = av.z; As[lk + 3][lr] = av.w;
    Bs[lk + 0][lr] = bv.x; Bs[lk + 1][lr] = bv.y;
    Bs[lk + 2][lr] = bv.z; Bs[lk + 3][lr] = bv.w;
    __syncthreads();
#pragma unroll
    for (int kk = 0; kk < 16; kk++) {
      float4 a4 = *(const float4*)&As[kk][ty * 4];
      float4 b4 = *(const float4*)&Bs[kk][tx * 4];
      float aa[4] = {a4.x, a4.y, a4.z, a4.w};
      float bb[4] = {b4.x, b4.y, b4.z, b4.w};
#pragma unroll
      for (int i = 0; i < 4; i++)
#pragma unroll
        for (int j = 0; j < 4; j++) acc[i][j] += aa[i] * bb[j];
    }
  }
#pragma unroll
  for (int i = 0; i < 4; i++) {
    float4 o = {acc[i][0], acc[i][1], acc[i][2], acc[i][3]};
    *(float4*)(C + (size_t)(m0 + ty * 4 + i) * 512 + n0 + tx * 4) = o;
  }
}

__global__ __launch_bounds__(256) void direct_kernel(
    const float* __restrict__ aQ, const float* __restrict__ aK,
    const float* __restrict__ Vp, const float* __restrict__ bias,
    float* __restrict__ out) {
  int id = blockIdx.x;
  int qt = id & 15, h = (id >> 4) & 7, b = id >> 7;
  __shared__ float AK[1024], E1s[1024], E2s[1024];
  __shared__ __align__(16) float VT[128][64];
  __shared__ float XQ[64];
  int t = threadIdx.x;
  for (int i = t; i < 1024; i += 256) {
    float a = aK[(size_t)(b * 1024 + i) * 8 + h];
    AK[i] = a; E1s[i] = __expf(a); E2s[i] = __expf(NS * a);
  }
  if (t < 64) XQ[t] = aQ[(size_t)(b * 1024 + qt * 64 + t) * 8 + h];
  __syncthreads();
  int w = t >> 6, d = t & 63;
  float xq[16], ex[16], e2x[16], acc[16], z[16];
#pragma unroll
  for (int qi = 0; qi < 16; qi++) {
    float x = XQ[w * 16 + qi];
    xq[qi] = x; ex[qi] = __expf(x); e2x[qi] = __expf(NS * x);
    acc[qi] = 0.f; z[qi] = 0.f;
  }
  for (int kt = 0; kt < 8; kt++) {
    __syncthreads();
    for (int i = t; i < 128 * 64; i += 256) {
      VT[i >> 6][i & 63] =
          Vp[(size_t)(b * 1024 + kt * 128 + (i >> 6)) * 512 + h * 64 + (i & 63)];
    }
    __syncthreads();
    for (int kk = 0; kk < 128; kk++) {
      int k = kt * 128 + kk;
      float a = AK[k], e1 = E1s[k], e2 = E2s[k];
      float v = VT[kk][d];
#pragma unroll
      for (int qi = 0; qi < 16; qi++) {
        float wsel = (a + xq[qi] > 0.f) ? (ex[qi] * e1) : (e2x[qi] * e2);
        acc[qi] += wsel * v;
        z[qi] += wsel;
      }
    }
  }
#pragma unroll
  for (int qi = 0; qi < 16; qi++) {
    int q = qt * 64 + w * 16 + qi;
    out[(size_t)(b * 1024 + q) * 512 + h * 64 + d] =
        acc[qi] / z[qi] + bias[h * 64 + d];
  }
}

// ---------------------------------------------------------------------------
extern "C" void kernel_launch(void* const* d_in, const int* in_sizes, int n_in,
                              void* d_out, int out_size, void* d_ws,
                              size_t ws_size, hipStream_t stream) {
  const float* Q = (const float*)d_in[0];
  const float* K = (const float*)d_in[1];
  const float* V = (const float*)d_in[2];
  const float* WQ = (const float*)d_in[3];
  const float* WK = (const float*)d_in[4];
  const float* WV = (const float*)d_in[5];
  const float* bias = (const float*)d_in[6];
  float* out = (float*)d_out;
  char* ws = (char*)d_ws;

  // byte offsets (16B aligned)
  const size_t oAQ   = 0;                   // f32 [8192][8]      256 KB
  const size_t oAK   = 262144;              // f32 [8192][8]      256 KB
  const size_t oE1   = 524288;              // f32 [64][1024]     256 KB
  const size_t oE2   = 786432;              // f32 [64][1024]     256 KB
  const size_t oIDX  = 1048576;             // i32 [64][1024]     256 KB
  const size_t oCOF1 = 1310720;             // f32 [64][32][64]   512 KB
  const size_t oCOF2 = 1835008;             // f32 [64][32][64]   512 KB
  const size_t oSC1  = 2359296;             // f32 [64][32]  (pad 16K)
  const size_t oSC2  = 2375680;
  const size_t oAMX  = 2392064;             // f32 [64]      (pad 4K)
  const size_t oBST  = 2396160;             // i32 [64][33]  (pad 16K)
  const size_t oBDA  = 2412544;             // i32 [64][1024]     256 KB
  const size_t oBX   = 2674688;             // f32 [64][1024]     256 KB
  const size_t oVP   = 2936832;             // f16 [8192][512]    8 MB
  const size_t NEED_MAIN = oVP + 8388608;   // ~10.8 MB
  const size_t NEED_FB = 524288 + 16777216; // ~17 MB

  if (ws_size >= NEED_MAIN) {
    float* aQ = (float*)(ws + oAQ);
    float* aK = (float*)(ws + oAK);
    float* E1g = (float*)(ws + oE1);
    float* E2g = (float*)(ws + oE2);
    int* IDXg = (int*)(ws + oIDX);
    float* cofs1 = (float*)(ws + oCOF1);
    float* cofs2 = (float*)(ws + oCOF2);
    float* scof1 = (float*)(ws + oSC1);
    float* scof2 = (float*)(ws + oSC2);
    float* amaxA = (float*)(ws + oAMX);
    int* binSt = (int*)(ws + oBST);
    int* binDa = (int*)(ws + oBDA);
    float* binX = (float*)(ws + oBX);
    _Float16* Vp = (_Float16*)(ws + oVP);
    hipLaunchKernelGGL(projQK_kernel, dim3(4096), dim3(256), 0, stream, Q, K,
                       WQ, WK, aQ, aK);
    hipLaunchKernelGGL(vproj_mfma, dim3(128, 8), dim3(256), 0, stream, V, WV,
                       Vp);
    hipLaunchKernelGGL(sortbin_kernel, dim3(64), dim3(1024), 0, stream, aK, aQ,
                       Vp, E1g, E2g, IDXg, cofs1, cofs2, scof1, scof2, amaxA,
                       binSt, binDa, binX);
    hipLaunchKernelGGL(final_binned, dim3(2048), dim3(256), 0, stream, E1g,
                       E2g, IDXg, Vp, cofs1, cofs2, scof1, scof2, amaxA, binSt,
                       binDa, binX, aQ, bias, out);
  } else if (ws_size >= NEED_FB) {
    float* aQ = (float*)(ws + 0);
    float* aK = (float*)(ws + 262144);
    float* Vpf = (float*)(ws + 524288);
    hipLaunchKernelGGL(projQK_kernel, dim3(4096), dim3(256), 0, stream, Q, K,
                       WQ, WK, aQ, aK);
    hipLaunchKernelGGL(vproj_gemm, dim3(128, 8), dim3(256), 0, stream, V, WV,
                       Vpf);
    hipLaunchKernelGGL(direct_kernel, dim3(1024), dim3(256), 0, stream, aQ, aK,
                       Vpf, bias, out);
  }
}